// Round 1
// baseline (816.977 us; speedup 1.0000x reference)
//
#include <hip/hip_runtime.h>

// MergedEmbeddingBag: T tables EmbeddingBag(sum) + dense concat.
// out[b, 0:D]          = dense[b]
// out[b, (t+1)*D : +D] = sum_{l in bag} weights[t, index[t, off..off+1], :]
constexpr int T = 26, B = 4096, L = 10, V = 50000, D = 128;
constexpr int N = B * L;
constexpr int SLOTS = T + 1;       // dense + T tables
constexpr int D4 = D / 4;          // 32 float4 per row

typedef float vfloat4 __attribute__((ext_vector_type(4)));

__global__ __launch_bounds__(256) void merged_embbag_kernel(
    const int* __restrict__ index,      // [T, N]
    const int* __restrict__ offsets,    // [T, B+1]
    const float* __restrict__ dense,    // [B, D]
    const float* __restrict__ weights,  // [T, V, D]
    float* __restrict__ out)            // [B, SLOTS*D]
{
    const int tid = blockIdx.x * blockDim.x + threadIdx.x;
    const int total = SLOTS * B * D4;
    if (tid >= total) return;

    const int d4 = tid & (D4 - 1);          // float4 index within row
    const int slot_b = tid >> 5;            // (b, slot) pair
    const int b = slot_b / SLOTS;
    const int slot = slot_b - b * SLOTS;

    vfloat4 acc;
    if (slot == 0) {
        // dense passthrough
        acc = reinterpret_cast<const vfloat4*>(dense)[b * D4 + d4];
    } else {
        const int t = slot - 1;
        const int* off = offsets + t * (B + 1);
        const int start = off[b];
        const int cnt = off[b + 1] - start;
        const int* ip = index + t * N + start;
        const float* Wt = weights + (size_t)t * ((size_t)V * (size_t)D);
        acc = (vfloat4)(0.f);
        if (cnt == L) {
            // fast path: preload all indices, then issue all gathers (MLP)
            int ix[L];
            #pragma unroll
            for (int l = 0; l < L; ++l) ix[l] = ip[l];
            #pragma unroll
            for (int l = 0; l < L; ++l) {
                vfloat4 v = *reinterpret_cast<const vfloat4*>(
                    Wt + (size_t)ix[l] * D + d4 * 4);
                acc += v;
            }
        } else {
            for (int l = 0; l < cnt; ++l) {
                vfloat4 v = *reinterpret_cast<const vfloat4*>(
                    Wt + (size_t)ip[l] * D + d4 * 4);
                acc += v;
            }
        }
    }
    // write-once output: nontemporal to keep L2/L3 for the gather stream.
    // out addr = b*(SLOTS*D) + slot*D + d4*4 = tid*4  -> out4[tid]
    __builtin_nontemporal_store(acc, reinterpret_cast<vfloat4*>(out) + tid);
}

extern "C" void kernel_launch(void* const* d_in, const int* in_sizes, int n_in,
                              void* d_out, int out_size, void* d_ws, size_t ws_size,
                              hipStream_t stream) {
    const int*   index   = (const int*)d_in[0];
    const int*   offsets = (const int*)d_in[1];
    const float* dense   = (const float*)d_in[2];
    const float* weights = (const float*)d_in[3];
    float* out = (float*)d_out;

    const int total = SLOTS * B * D4;          // 3,538,944 threads
    const int block = 256;
    const int grid = (total + block - 1) / block;  // 13824
    merged_embbag_kernel<<<grid, block, 0, stream>>>(index, offsets, dense, weights, out);
}